// Round 2
// baseline (389.095 us; speedup 1.0000x reference)
//
#include <hip/hip_runtime.h>
#include <hip/hip_bf16.h>
#include <cstdint>

// ---------- types ----------
typedef __attribute__((ext_vector_type(8))) short short8;     // 8 x bf16 raw
typedef __attribute__((ext_vector_type(4))) short short4v;    // 4 x bf16 raw
typedef __attribute__((ext_vector_type(4))) float floatx4;
typedef __attribute__((ext_vector_type(4))) unsigned short ushort4v;

// ---------- helpers ----------
__device__ __forceinline__ float bf2f(unsigned short u) {
    union { unsigned int u; float f; } v;
    v.u = ((unsigned int)u) << 16;
    return v.f;
}
__device__ __forceinline__ unsigned short f2bf(float f) {
    union { float f; unsigned int u; } v; v.f = f;
    unsigned int u = v.u;
    unsigned int r = (u + 0x7FFFu + ((u >> 16) & 1u)) >> 16;  // RNE
    return (unsigned short)r;
}
__device__ __forceinline__ float lo_bf(unsigned int u) {
    union { unsigned int u; float f; } v; v.u = u << 16; return v.f;
}
__device__ __forceinline__ float hi_bf(unsigned int u) {
    union { unsigned int u; float f; } v; v.u = u & 0xffff0000u; return v.f;
}
__device__ __forceinline__ void gld_lds16(const void* g, void* l) {
    __builtin_amdgcn_global_load_lds(
        (const __attribute__((address_space(1))) unsigned int*)g,
        (__attribute__((address_space(3))) unsigned int*)l,
        16, 0, 0);
}

// ---------- unified prep: feature cvt + all weight transposes, ONE dispatch ----------
__global__ __launch_bounds__(256) void prep_kernel(
    const float* __restrict__ f1, const float* __restrict__ f2,
    unsigned short* __restrict__ f1b, unsigned short* __restrict__ f2b,
    const float* __restrict__ W1, unsigned short* __restrict__ W1t,
    const float* __restrict__ W2, unsigned short* __restrict__ W2t,
    const float* __restrict__ Wqkv, unsigned short* __restrict__ Wqkvt,
    const float* __restrict__ Wout, unsigned short* __restrict__ Woutt) {
    __shared__ float tile[64][33];
    const int b = blockIdx.x;
    const int tid = threadIdx.x;

    if (b < 5632) {
        const float* in = (b < 4096) ? f1 : f2;
        unsigned short* outp = (b < 4096) ? f1b : f2b;
        int base = ((b < 4096) ? b : (b - 4096)) * 1024 + tid;
#pragma unroll
        for (int it = 0; it < 4; it++) {
            int i = base + it * 256;
            float4 v = ((const float4*)in)[i];
            ushort4v o;
            o.x = f2bf(v.x); o.y = f2bf(v.y); o.z = f2bf(v.z); o.w = f2bf(v.w);
            ((ushort4v*)outp)[i] = o;
        }
        return;
    }

    const float* in; unsigned short* outp; int K, N, t;
    if (b < 6656)      { in = W1;   outp = W1t;   K = 2048; N = 1024; t = b - 5632; }
    else if (b < 7040) { in = W2;   outp = W2t;   K = 768;  N = 1024; t = b - 6656; }
    else if (b < 8576) { in = Wqkv; outp = Wqkvt; K = 1024; N = 3072; t = b - 7040; }
    else               { in = Wout; outp = Woutt; K = 1024; N = 1024; t = b - 8576; }
    const int ntiles = N >> 5;
    const int n0 = (t % ntiles) * 32;
    const int k0 = (t / ntiles) * 64;
    const int tx = tid & 31, tg = tid >> 5;
#pragma unroll
    for (int i = 0; i < 8; i++)
        tile[tg * 8 + i][tx] = in[(size_t)(k0 + tg * 8 + i) * N + n0 + tx];
    __syncthreads();
    const int n = tid >> 3, kc = (tid & 7) * 8;
    short8 o;
#pragma unroll
    for (int j = 0; j < 8; j++) o[j] = (short)f2bf(tile[kc + j][n]);
    *(short8*)&outp[(size_t)(n0 + n) * K + k0 + kc] = o;
}

// ---------- bf16 GEMM core, BK=64 (swizzled LDS, verified r1) ----------
template <bool OUT_BF16, bool HAS_BIAS>
__device__ __forceinline__ void gemm_core(const unsigned short* __restrict__ A,
                                          const unsigned short* __restrict__ Bt,
                                          void* __restrict__ Cv, const float* __restrict__ bias,
                                          int K, int ldc, int blockM, int blockN,
                                          unsigned short* As, unsigned short* Bs) {
    const int tid  = threadIdx.x;
    const int lane = tid & 63;
    const int wave = tid >> 6;
    const int wm = wave >> 1, wn = wave & 1;

    const int kx = (tid >> 3) & 3;
    const unsigned short* gA = A  + (size_t)(blockM + (tid >> 2)) * K + ((tid & 3) ^ kx) * 8;
    const unsigned short* gB = Bt + (size_t)(blockN + (tid >> 2)) * K + ((tid & 3) ^ kx) * 8;
    const size_t sK = (size_t)64 * K;
    unsigned short* lA = As + wave * 512;
    unsigned short* lB = Bs + wave * 512;

    floatx4 acc[4][4];
#pragma unroll
    for (int i = 0; i < 4; i++)
#pragma unroll
        for (int j = 0; j < 4; j++) acc[i][j] = (floatx4){0.f, 0.f, 0.f, 0.f};

    const int col  = lane & 15;
    const int quad = lane >> 4;
    const int qx = quad ^ ((col >> 1) & 3);
    const int aoff32 = (wm * 64 + col) * 32 + qx * 8;
    const int boff32 = (wn * 64 + col) * 32 + qx * 8;

    const int kIters = K >> 6;
    for (int kt = 0; kt < kIters; ++kt) {
        const size_t ko = (size_t)kt * 64;
        gld_lds16(gA + ko,           lA);
        gld_lds16(gA + sK + ko,      lA + 2048);
        gld_lds16(gA + 32 + ko,      lA + 4096);
        gld_lds16(gA + sK + 32 + ko, lA + 6144);
        gld_lds16(gB + ko,           lB);
        gld_lds16(gB + sK + ko,      lB + 2048);
        gld_lds16(gB + 32 + ko,      lB + 4096);
        gld_lds16(gB + sK + 32 + ko, lB + 6144);
        __syncthreads();

#pragma unroll
        for (int hh = 0; hh < 2; hh++) {
            short8 a[4];
#pragma unroll
            for (int i = 0; i < 4; i++) a[i] = *(const short8*)&As[hh * 4096 + aoff32 + i * 512];
#pragma unroll
            for (int j = 0; j < 4; j++) {
                short8 bj = *(const short8*)&Bs[hh * 4096 + boff32 + j * 512];
#pragma unroll
                for (int i = 0; i < 4; i++)
                    acc[i][j] = __builtin_amdgcn_mfma_f32_16x16x32_bf16(a[i], bj, acc[i][j], 0, 0, 0);
            }
        }
        __syncthreads();
    }

#pragma unroll
    for (int i = 0; i < 4; i++) {
#pragma unroll
        for (int j = 0; j < 4; j++) {
#pragma unroll
            for (int r = 0; r < 4; r++) {
                int row = blockM + wm * 64 + i * 16 + quad * 4 + r;
                int cn  = blockN + wn * 64 + j * 16 + col;
                float v = acc[i][j][r];
                if (HAS_BIAS) v += bias[cn];
                if (OUT_BF16) ((unsigned short*)Cv)[(size_t)row * ldc + cn] = f2bf(v);
                else          ((float*)Cv)[(size_t)row * ldc + cn] = v;
            }
        }
    }
}

__global__ __launch_bounds__(256, 3)
void gemm_f12(const unsigned short* __restrict__ f1b, const unsigned short* __restrict__ W1t,
              const float* __restrict__ b1,
              const unsigned short* __restrict__ f2b, const unsigned short* __restrict__ W2t,
              const float* __restrict__ b2, unsigned short* __restrict__ xb) {
    __shared__ alignas(16) unsigned short As[8192];
    __shared__ alignas(16) unsigned short Bs[8192];
    const int blockM = blockIdx.x * 128;
    const int blockN = blockIdx.y * 128;
    if (blockIdx.z == 0)
        gemm_core<true, true>(f1b, W1t, (void*)xb, b1, 2048, 2048, blockM, blockN, As, Bs);
    else
        gemm_core<true, true>(f2b, W2t, (void*)(xb + 1024), b2, 768, 2048, blockM, blockN, As, Bs);
}

__global__ __launch_bounds__(256, 3)
void gemm_proj(const unsigned short* __restrict__ attn, const unsigned short* __restrict__ Woutt,
               const float* __restrict__ bout, unsigned short* __restrict__ projb) {
    __shared__ alignas(16) unsigned short As[8192];
    __shared__ alignas(16) unsigned short Bs[8192];
    gemm_core<true, true>(attn, Woutt, (void*)projb, bout, 1024, 1024,
                          blockIdx.x * 128, blockIdx.y * 128, As, Bs);
}

// ---------- fused qkv GEMM + 2x2 attention, 8-phase-style pipeline ----------
// BM=256, BN=192 (q|k|v of one head), BK=64, 512 thr / 8 waves, dbuf LDS.
// Per K-tile: 4 phases x 12 MFMA; stage(t+1) issued in P0/P1 of tile t, drained
// by the __syncthreads at top of tile t+1 (~3.5 phases of latency coverage).
// LDS byte map: buf0 A[256][64]@0 (32KiB) B[192][64]@32768 (24KiB); buf1 @57344;
//               wsm @114688 (2KiB); T2 overlay 192x264 bf16 @0 (epilogue only).
#define QKV_LDS_BYTES 116736
#define T2_ST 264
__global__ __launch_bounds__(512, 2)
void gemm_qkv_attn2(const unsigned short* __restrict__ A, const unsigned short* __restrict__ Bt,
                    unsigned short* __restrict__ attn_out) {
    extern __shared__ __align__(16) char smem[];
    unsigned short* buf0 = (unsigned short*)smem;
    unsigned short* buf1 = (unsigned short*)(smem + 57344);
    unsigned short* T2   = (unsigned short*)smem;
    float* wsm = (float*)(smem + 114688);

    const int tid  = threadIdx.x;
    const int lane = tid & 63;
    const int wave = tid >> 6;
    const int wm = wave >> 1;                 // 0..3 -> 64-row slice
    const int wn = wave & 1;                  // 0..1 -> 96-col slice
    const int g = blockIdx.x;
    const int h = g >> 6;                     // head 0..15
    const int blockM = (g & 63) * 256;        // m fastest: same m, all h -> same XCD (64%8==0)
    const int K = 1024;

    // staging: round = 64 rows x 8 chunks(16B); lane l -> row l>>3, lds chunk l&7,
    // global chunk (l&7)^(row&7)  [swizzle on source, LDS linear — rule #21]
    const int srow = tid >> 3;                // 0..63
    const int schunk = (tid & 7) ^ (srow & 7);
    const unsigned short* gA = A  + (size_t)(blockM + srow) * K + schunk * 8;
    const unsigned short* gB = Bt + (size_t)(h * 64 + srow) * K + schunk * 8;
    const int sdst = wave * 512;              // wave base (elems) within a round block

#define STAGE_A(bufp, koff) do { \
    gld_lds16(gA + (koff),          (bufp) + sdst);          \
    gld_lds16(gA + 65536 + (koff),  (bufp) + 4096 + sdst);   \
    gld_lds16(gA + 131072 + (koff), (bufp) + 8192 + sdst);   \
    gld_lds16(gA + 196608 + (koff), (bufp) + 12288 + sdst); } while (0)
#define STAGE_B(bufp, koff) do { \
    gld_lds16(gB + (koff),           (bufp) + 16384 + sdst);         \
    gld_lds16(gB + 1048576 + (koff), (bufp) + 16384 + 4096 + sdst);  \
    gld_lds16(gB + 2097152 + (koff), (bufp) + 16384 + 8192 + sdst); } while (0)

    floatx4 acc[4][6];
#pragma unroll
    for (int i = 0; i < 4; i++)
#pragma unroll
        for (int j = 0; j < 6; j++) acc[i][j] = (floatx4){0.f, 0.f, 0.f, 0.f};

    const int col  = lane & 15;
    const int quad = lane >> 4;
    const int ch0  = (quad ^ (col & 7)) * 8;  // hh=0 swizzled chunk (elems); hh=1: ^32
    int aoff[4], boff[6];
#pragma unroll
    for (int i = 0; i < 4; i++) aoff[i] = (wm * 64 + i * 16 + col) * 64 + ch0;
#pragma unroll
    for (int j = 0; j < 6; j++) boff[j] = 16384 + (wn * 96 + j * 16 + col) * 64 + ch0;

    // prologue: stage tile 0
    STAGE_A(buf0, 0);
    STAGE_B(buf0, 0);

    for (int kt = 0; kt < 16; ++kt) {
        unsigned short* cur = (kt & 1) ? buf1 : buf0;
        unsigned short* nxt = (kt & 1) ? buf0 : buf1;
        const int kn = (kt + 1) * 64;
        __syncthreads();   // drains vmcnt(0): tile kt landed in cur (all waves)

        // ---- P0: a(h0)[4] + b(h0)[0..2]; stage A(t+1) ----
        short8 a0[4], b0v[3];
#pragma unroll
        for (int i = 0; i < 4; i++) a0[i] = *(const short8*)&cur[aoff[i]];
#pragma unroll
        for (int j = 0; j < 3; j++) b0v[j] = *(const short8*)&cur[boff[j]];
        if (kt < 15) { STAGE_A(nxt, kn); }
        __builtin_amdgcn_sched_barrier(0);
        __builtin_amdgcn_s_barrier();
        asm volatile("s_waitcnt lgkmcnt(0)" ::: "memory");
        __builtin_amdgcn_sched_barrier(0);
        __builtin_amdgcn_s_setprio(1);
#pragma unroll
        for (int j = 0; j < 3; j++)
#pragma unroll
            for (int i = 0; i < 4; i++)
                acc[i][j] = __builtin_amdgcn_mfma_f32_16x16x32_bf16(a0[i], b0v[j], acc[i][j], 0, 0, 0);
        __builtin_amdgcn_s_setprio(0);
        __builtin_amdgcn_sched_barrier(0);
        __builtin_amdgcn_s_barrier();

        // ---- P1: b(h0)[3..5]; stage B(t+1) ----
        short8 b1v[3];
#pragma unroll
        for (int j = 0; j < 3; j++) b1v[j] = *(const short8*)&cur[boff[3 + j]];
        if (kt < 15) { STAGE_B(nxt, kn); }
        __builtin_amdgcn_sched_barrier(0);
        __builtin_amdgcn_s_barrier();
        asm volatile("s_waitcnt lgkmcnt(0)" ::: "memory");
        __builtin_amdgcn_sched_barrier(0);
        __builtin_amdgcn_s_setprio(1);
#pragma unroll
        for (int j = 0; j < 3; j++)
#pragma unroll
            for (int i = 0; i < 4; i++)
                acc[i][3 + j] = __builtin_amdgcn_mfma_f32_16x16x32_bf16(a0[i], b1v[j], acc[i][3 + j], 0, 0, 0);
        __builtin_amdgcn_s_setprio(0);
        __builtin_amdgcn_sched_barrier(0);
        __builtin_amdgcn_s_barrier();

        // ---- P2: a(h1)[4] + b(h1)[0..2] ----
        short8 a1[4], b2v[3];
#pragma unroll
        for (int i = 0; i < 4; i++) a1[i] = *(const short8*)&cur[aoff[i] ^ 32];
#pragma unroll
        for (int j = 0; j < 3; j++) b2v[j] = *(const short8*)&cur[boff[j] ^ 32];
        __builtin_amdgcn_sched_barrier(0);
        __builtin_amdgcn_s_barrier();
        asm volatile("s_waitcnt lgkmcnt(0)" ::: "memory");
        __builtin_amdgcn_sched_barrier(0);
        __builtin_amdgcn_s_setprio(1);
#pragma unroll
        for (int j = 0; j < 3; j++)
#pragma unroll
            for (int i = 0; i < 4; i++)
                acc[i][j] = __builtin_amdgcn_mfma_f32_16x16x32_bf16(a1[i], b2v[j], acc[i][j], 0, 0, 0);
        __builtin_amdgcn_s_setprio(0);
        __builtin_amdgcn_sched_barrier(0);
        __builtin_amdgcn_s_barrier();

        // ---- P3: b(h1)[3..5] ----
        short8 b3v[3];
#pragma unroll
        for (int j = 0; j < 3; j++) b3v[j] = *(const short8*)&cur[boff[3 + j] ^ 32];
        __builtin_amdgcn_sched_barrier(0);
        __builtin_amdgcn_s_barrier();
        asm volatile("s_waitcnt lgkmcnt(0)" ::: "memory");
        __builtin_amdgcn_sched_barrier(0);
        __builtin_amdgcn_s_setprio(1);
#pragma unroll
        for (int j = 0; j < 3; j++)
#pragma unroll
            for (int i = 0; i < 4; i++)
                acc[i][3 + j] = __builtin_amdgcn_mfma_f32_16x16x32_bf16(a1[i], b3v[j], acc[i][3 + j], 0, 0, 0);
        __builtin_amdgcn_s_setprio(0);
        // loop-top __syncthreads closes the phase
    }
    __syncthreads();
#undef STAGE_A
#undef STAGE_B

    // 1) store tile transposed into overlay: T2[c][r], c = feature (q|k|v), r = M-row
#pragma unroll
    for (int i = 0; i < 4; i++) {
#pragma unroll
        for (int j = 0; j < 6; j++) {
            int c  = wn * 96 + j * 16 + col;
            int r0 = wm * 64 + i * 16 + quad * 4;
            short4v pk;
            pk.x = (short)f2bf(acc[i][j][0]);
            pk.y = (short)f2bf(acc[i][j][1]);
            pk.z = (short)f2bf(acc[i][j][2]);
            pk.w = (short)f2bf(acc[i][j][3]);
            *(short4v*)&T2[c * T2_ST + r0] = pk;
        }
    }
    __syncthreads();

    // 2) scores + softmax: thread ib (<128) handles batch-row pair (2ib, 2ib+1)
    if (tid < 128) {
        const int ib = tid;
        float s00 = 0.f, s01 = 0.f, s10 = 0.f, s11 = 0.f;
#pragma unroll 8
        for (int d = 0; d < 64; d++) {
            unsigned int qp = *(const unsigned int*)&T2[d * T2_ST + 2 * ib];
            unsigned int kp = *(const unsigned int*)&T2[(64 + d) * T2_ST + 2 * ib];
            float q0 = lo_bf(qp), q1 = hi_bf(qp);
            float k0 = lo_bf(kp), k1 = hi_bf(kp);
            s00 += q0 * k0; s01 += q0 * k1;
            s10 += q1 * k0; s11 += q1 * k1;
        }
        const float sc = 0.125f;   // (1024/16)^-0.5
        s00 *= sc; s01 *= sc; s10 *= sc; s11 *= sc;
        float m0 = fmaxf(s00, s01), m1 = fmaxf(s10, s11);
        float e00 = __expf(s00 - m0), e01 = __expf(s01 - m0);
        float e10 = __expf(s10 - m1), e11 = __expf(s11 - m1);
        float i0 = 1.f / (e00 + e01), i1 = 1.f / (e10 + e11);
        wsm[ib * 4 + 0] = e00 * i0; wsm[ib * 4 + 1] = e01 * i0;
        wsm[ib * 4 + 2] = e10 * i1; wsm[ib * 4 + 3] = e11 * i1;
    }
    __syncthreads();

    // 3) out = attn @ v, write global (256 rows x 64 cols = 2048 8-elem chunks)
#pragma unroll
    for (int gg = 0; gg < 4; gg++) {
        int chunk = gg * 512 + tid;
        int r = chunk >> 3;
        int dc = (chunk & 7) * 8;
        int ib = r >> 1, n = r & 1;
        float w0 = wsm[ib * 4 + n * 2 + 0];
        float w1 = wsm[ib * 4 + n * 2 + 1];
        short8 o;
#pragma unroll
        for (int dd = 0; dd < 8; dd++) {
            unsigned int vp = *(const unsigned int*)&T2[(128 + dc + dd) * T2_ST + 2 * ib];
            o[dd] = (short)f2bf(w0 * lo_bf(vp) + w1 * hi_bf(vp));
        }
        *(short8*)&attn_out[(size_t)(blockM + r) * 1024 + h * 64 + dc] = o;
    }
}

// ---------- LayerNorm(2048) + residual ----------
__global__ __launch_bounds__(256) void ln_res_kernel(const unsigned short* __restrict__ proj,
                                                     const unsigned short* __restrict__ xres,
                                                     const float* __restrict__ gamma,
                                                     const float* __restrict__ beta,
                                                     float* __restrict__ out) {
    const int b = blockIdx.x;
    const int tid = threadIdx.x;
    const size_t base = (size_t)b * 2048;
    short8 p8 = ((const short8*)(proj + base))[tid];
    float pv[8];
#pragma unroll
    for (int e = 0; e < 8; e++) pv[e] = bf2f((unsigned short)p8[e]);
    float s = 0.f, ss = 0.f;
#pragma unroll
    for (int e = 0; e < 8; e++) { s += pv[e]; ss += pv[e] * pv[e]; }
#pragma unroll
    for (int off = 32; off > 0; off >>= 1) {
        s  += __shfl_xor(s, off);
        ss += __shfl_xor(ss, off);
    }
    __shared__ float red[8];
    const int wave = tid >> 6;
    if ((tid & 63) == 0) { red[wave] = s; red[4 + wave] = ss; }
    __syncthreads();
    s  = red[0] + red[1] + red[2] + red[3];
    ss = red[4] + red[5] + red[6] + red[7];
    const float mean = s * (1.0f / 2048.0f);
    const float var  = ss * (1.0f / 2048.0f) - mean * mean;
    const float rstd = rsqrtf(var + 1e-5f);

    const float4* g4 = (const float4*)gamma;
    const float4* b4 = (const float4*)beta;
    float4 g0 = g4[2 * tid], g1 = g4[2 * tid + 1];
    float4 be0 = b4[2 * tid], be1 = b4[2 * tid + 1];
    short8 r8 = ((const short8*)(xres + base))[tid];
    float4 o0, o1;
    o0.x = (pv[0] - mean) * rstd * g0.x + be0.x + bf2f((unsigned short)r8[0]);
    o0.y = (pv[1] - mean) * rstd * g0.y + be0.y + bf2f((unsigned short)r8[1]);
    o0.z = (pv[2] - mean) * rstd * g0.z + be0.z + bf2f((unsigned short)r8[2]);
    o0.w = (pv[3] - mean) * rstd * g0.w + be0.w + bf2f((unsigned short)r8[3]);
    o1.x = (pv[4] - mean) * rstd * g1.x + be1.x + bf2f((unsigned short)r8[4]);
    o1.y = (pv[5] - mean) * rstd * g1.y + be1.y + bf2f((unsigned short)r8[5]);
    o1.z = (pv[6] - mean) * rstd * g1.z + be1.z + bf2f((unsigned short)r8[6]);
    o1.w = (pv[7] - mean) * rstd * g1.w + be1.w + bf2f((unsigned short)r8[7]);
    float4* op = (float4*)(out + base);
    op[2 * tid] = o0;
    op[2 * tid + 1] = o1;
}

// ---------- launch ----------
extern "C" void kernel_launch(void* const* d_in, const int* in_sizes, int n_in,
                              void* d_out, int out_size, void* d_ws, size_t ws_size,
                              hipStream_t stream) {
    (void)in_sizes; (void)n_in; (void)out_size; (void)ws_size;
    const float* features1 = (const float*)d_in[0];
    const float* features2 = (const float*)d_in[1];
    const float* W1   = (const float*)d_in[2];
    const float* b1   = (const float*)d_in[3];
    const float* W2   = (const float*)d_in[4];
    const float* b2   = (const float*)d_in[5];
    const float* Wqkv = (const float*)d_in[6];
    const float* Wout = (const float*)d_in[7];
    const float* bout = (const float*)d_in[8];
    const float* gamma = (const float*)d_in[9];
    const float* beta  = (const float*)d_in[10];
    float* out = (float*)d_out;

    static bool qkv2_init = false;
    if (!qkv2_init) {
        (void)hipFuncSetAttribute((const void*)gemm_qkv_attn2,
                                  hipFuncAttributeMaxDynamicSharedMemorySize,
                                  QKV_LDS_BYTES);
        qkv2_init = true;
    }

    // B=8192, IMG=2048, Q=768, H=1024
    char* ws = (char*)d_ws;
    unsigned short* f1b   = (unsigned short*)(ws);                 // 32 MiB
    unsigned short* f2b   = (unsigned short*)(ws + 33554432);      // 12 MiB
    unsigned short* W1t   = (unsigned short*)(ws + 46137344);      // 4 MiB   [1024][2048]
    unsigned short* W2t   = (unsigned short*)(ws + 50331648);      // 1.5 MiB [1024][768]
    unsigned short* Wqkvt = (unsigned short*)(ws + 51904512);      // 6 MiB   [3072][1024]
    unsigned short* Woutt = (unsigned short*)(ws + 58195968);      // 2 MiB   [1024][1024]
    unsigned short* xb    = (unsigned short*)(ws + 60293120);      // 32 MiB  [16384][1024]
    unsigned short* attn  = (unsigned short*)(ws + 93847552);      // 32 MiB  [16384][1024]
    unsigned short* projb = (unsigned short*)(ws + 127401984);     // 32 MiB  [16384][1024] bf16

    // 1) unified prep (feature cvt + weight transposes)
    prep_kernel<<<9088, 256, 0, stream>>>(features1, features2, f1b, f2b,
                                          W1, W1t, W2, W2t, Wqkv, Wqkvt, Wout, Woutt);
    // 2) f1/f2 modality GEMMs
    gemm_f12<<<dim3(64, 8, 2), 256, 0, stream>>>(f1b, W1t, b1, f2b, W2t, b2, xb);
    // 3) fused qkv GEMM + attention (8-phase pipeline, BM=256)
    gemm_qkv_attn2<<<1024, 512, QKV_LDS_BYTES, stream>>>(xb, Wqkvt, attn);
    // 4) proj = attn @ Wout + bout -> bf16
    gemm_proj<<<dim3(128, 8), 256, 0, stream>>>(attn, Woutt, bout, projb);
    // 5) LayerNorm + residual
    ln_res_kernel<<<8192, 256, 0, stream>>>(projb, xb, gamma, beta, out);
}

// Round 3
// 370.363 us; speedup vs baseline: 1.0506x; 1.0506x over previous
//
#include <hip/hip_runtime.h>
#include <hip/hip_bf16.h>
#include <cstdint>

// ---------- types ----------
typedef __attribute__((ext_vector_type(8))) short short8;     // 8 x bf16 raw
typedef __attribute__((ext_vector_type(4))) short short4v;    // 4 x bf16 raw
typedef __attribute__((ext_vector_type(4))) float floatx4;
typedef __attribute__((ext_vector_type(4))) unsigned short ushort4v;

// ---------- helpers ----------
__device__ __forceinline__ float bf2f(unsigned short u) {
    union { unsigned int u; float f; } v;
    v.u = ((unsigned int)u) << 16;
    return v.f;
}
__device__ __forceinline__ unsigned short f2bf(float f) {
    union { float f; unsigned int u; } v; v.f = f;
    unsigned int u = v.u;
    unsigned int r = (u + 0x7FFFu + ((u >> 16) & 1u)) >> 16;  // RNE
    return (unsigned short)r;
}
__device__ __forceinline__ float lo_bf(unsigned int u) {
    union { unsigned int u; float f; } v; v.u = u << 16; return v.f;
}
__device__ __forceinline__ float hi_bf(unsigned int u) {
    union { unsigned int u; float f; } v; v.u = u & 0xffff0000u; return v.f;
}
__device__ __forceinline__ void gld_lds16(const void* g, void* l) {
    __builtin_amdgcn_global_load_lds(
        (const __attribute__((address_space(1))) unsigned int*)g,
        (__attribute__((address_space(3))) unsigned int*)l,
        16, 0, 0);
}

// ---------- unified prep: feature cvt + all weight transposes, ONE dispatch ----------
__global__ __launch_bounds__(256) void prep_kernel(
    const float* __restrict__ f1, const float* __restrict__ f2,
    unsigned short* __restrict__ f1b, unsigned short* __restrict__ f2b,
    const float* __restrict__ W1, unsigned short* __restrict__ W1t,
    const float* __restrict__ W2, unsigned short* __restrict__ W2t,
    const float* __restrict__ Wqkv, unsigned short* __restrict__ Wqkvt,
    const float* __restrict__ Wout, unsigned short* __restrict__ Woutt) {
    __shared__ float tile[64][33];
    const int b = blockIdx.x;
    const int tid = threadIdx.x;

    if (b < 5632) {
        const float* in = (b < 4096) ? f1 : f2;
        unsigned short* outp = (b < 4096) ? f1b : f2b;
        int base = ((b < 4096) ? b : (b - 4096)) * 1024 + tid;
#pragma unroll
        for (int it = 0; it < 4; it++) {
            int i = base + it * 256;
            float4 v = ((const float4*)in)[i];
            ushort4v o;
            o.x = f2bf(v.x); o.y = f2bf(v.y); o.z = f2bf(v.z); o.w = f2bf(v.w);
            ((ushort4v*)outp)[i] = o;
        }
        return;
    }

    const float* in; unsigned short* outp; int K, N, t;
    if (b < 6656)      { in = W1;   outp = W1t;   K = 2048; N = 1024; t = b - 5632; }
    else if (b < 7040) { in = W2;   outp = W2t;   K = 768;  N = 1024; t = b - 6656; }
    else if (b < 8576) { in = Wqkv; outp = Wqkvt; K = 1024; N = 3072; t = b - 7040; }
    else               { in = Wout; outp = Woutt; K = 1024; N = 1024; t = b - 8576; }
    const int ntiles = N >> 5;
    const int n0 = (t % ntiles) * 32;
    const int k0 = (t / ntiles) * 64;
    const int tx = tid & 31, tg = tid >> 5;
#pragma unroll
    for (int i = 0; i < 8; i++)
        tile[tg * 8 + i][tx] = in[(size_t)(k0 + tg * 8 + i) * N + n0 + tx];
    __syncthreads();
    const int n = tid >> 3, kc = (tid & 7) * 8;
    short8 o;
#pragma unroll
    for (int j = 0; j < 8; j++) o[j] = (short)f2bf(tile[kc + j][n]);
    *(short8*)&outp[(size_t)(n0 + n) * K + k0 + kc] = o;
}

// ---------- bf16 GEMM core, BK=64 (swizzled LDS, verified r1) ----------
template <bool OUT_BF16, bool HAS_BIAS>
__device__ __forceinline__ void gemm_core(const unsigned short* __restrict__ A,
                                          const unsigned short* __restrict__ Bt,
                                          void* __restrict__ Cv, const float* __restrict__ bias,
                                          int K, int ldc, int blockM, int blockN,
                                          unsigned short* As, unsigned short* Bs) {
    const int tid  = threadIdx.x;
    const int lane = tid & 63;
    const int wave = tid >> 6;
    const int wm = wave >> 1, wn = wave & 1;

    const int kx = (tid >> 3) & 3;
    const unsigned short* gA = A  + (size_t)(blockM + (tid >> 2)) * K + ((tid & 3) ^ kx) * 8;
    const unsigned short* gB = Bt + (size_t)(blockN + (tid >> 2)) * K + ((tid & 3) ^ kx) * 8;
    const size_t sK = (size_t)64 * K;
    unsigned short* lA = As + wave * 512;
    unsigned short* lB = Bs + wave * 512;

    floatx4 acc[4][4];
#pragma unroll
    for (int i = 0; i < 4; i++)
#pragma unroll
        for (int j = 0; j < 4; j++) acc[i][j] = (floatx4){0.f, 0.f, 0.f, 0.f};

    const int col  = lane & 15;
    const int quad = lane >> 4;
    const int qx = quad ^ ((col >> 1) & 3);
    const int aoff32 = (wm * 64 + col) * 32 + qx * 8;
    const int boff32 = (wn * 64 + col) * 32 + qx * 8;

    const int kIters = K >> 6;
    for (int kt = 0; kt < kIters; ++kt) {
        const size_t ko = (size_t)kt * 64;
        gld_lds16(gA + ko,           lA);
        gld_lds16(gA + sK + ko,      lA + 2048);
        gld_lds16(gA + 32 + ko,      lA + 4096);
        gld_lds16(gA + sK + 32 + ko, lA + 6144);
        gld_lds16(gB + ko,           lB);
        gld_lds16(gB + sK + ko,      lB + 2048);
        gld_lds16(gB + 32 + ko,      lB + 4096);
        gld_lds16(gB + sK + 32 + ko, lB + 6144);
        __syncthreads();

#pragma unroll
        for (int hh = 0; hh < 2; hh++) {
            short8 a[4];
#pragma unroll
            for (int i = 0; i < 4; i++) a[i] = *(const short8*)&As[hh * 4096 + aoff32 + i * 512];
#pragma unroll
            for (int j = 0; j < 4; j++) {
                short8 bj = *(const short8*)&Bs[hh * 4096 + boff32 + j * 512];
#pragma unroll
                for (int i = 0; i < 4; i++)
                    acc[i][j] = __builtin_amdgcn_mfma_f32_16x16x32_bf16(a[i], bj, acc[i][j], 0, 0, 0);
            }
        }
        __syncthreads();
    }

#pragma unroll
    for (int i = 0; i < 4; i++) {
#pragma unroll
        for (int j = 0; j < 4; j++) {
#pragma unroll
            for (int r = 0; r < 4; r++) {
                int row = blockM + wm * 64 + i * 16 + quad * 4 + r;
                int cn  = blockN + wn * 64 + j * 16 + col;
                float v = acc[i][j][r];
                if (HAS_BIAS) v += bias[cn];
                if (OUT_BF16) ((unsigned short*)Cv)[(size_t)row * ldc + cn] = f2bf(v);
                else          ((float*)Cv)[(size_t)row * ldc + cn] = v;
            }
        }
    }
}

__global__ __launch_bounds__(256, 3)
void gemm_f12(const unsigned short* __restrict__ f1b, const unsigned short* __restrict__ W1t,
              const float* __restrict__ b1,
              const unsigned short* __restrict__ f2b, const unsigned short* __restrict__ W2t,
              const float* __restrict__ b2, unsigned short* __restrict__ xb) {
    __shared__ alignas(16) unsigned short As[8192];
    __shared__ alignas(16) unsigned short Bs[8192];
    const int blockM = blockIdx.x * 128;
    const int blockN = blockIdx.y * 128;
    if (blockIdx.z == 0)
        gemm_core<true, true>(f1b, W1t, (void*)xb, b1, 2048, 2048, blockM, blockN, As, Bs);
    else
        gemm_core<true, true>(f2b, W2t, (void*)(xb + 1024), b2, 768, 2048, blockM, blockN, As, Bs);
}

__global__ __launch_bounds__(256, 3)
void gemm_proj(const unsigned short* __restrict__ attn, const unsigned short* __restrict__ Woutt,
               const float* __restrict__ bout, unsigned short* __restrict__ projb) {
    __shared__ alignas(16) unsigned short As[8192];
    __shared__ alignas(16) unsigned short Bs[8192];
    gemm_core<true, true>(attn, Woutt, (void*)projb, bout, 1024, 1024,
                          blockIdx.x * 128, blockIdx.y * 128, As, Bs);
}

// ---------- fused qkv GEMM + 2x2 attention, dbuf + counted vmcnt (T4) ----------
// r1 structure (128-tile, 256 thr, 4 waves, same LDS layout/swizzle) with:
//  - double-buffered staging (2 x 40960 B = 80 KiB -> 2 blocks/CU)
//  - STAGE(t+1) issued first, then s_waitcnt vmcnt(10): tile t's 10 loads land,
//    the 10 new stay in flight across BOTH barriers (never drained to 0 mid-loop)
//  - raw s_barrier (no implicit vmcnt(0)), lgkmcnt(0)+sched_barrier before MFMA (rule #18)
// Epilogue overlay: T2 192x132 bf16 @0 (50688 B), wsm @51200 (1 KiB) — within 80 KiB.
#define QKV_LDS_BYTES 81920
#define T2_ST 132
__global__ __launch_bounds__(256, 2)
void gemm_qkv_attn3(const unsigned short* __restrict__ A, const unsigned short* __restrict__ Bt,
                    unsigned short* __restrict__ attn_out) {
    extern __shared__ __align__(16) char smem[];
    unsigned short* buf0 = (unsigned short*)smem;       // 20480 elems: A 8192 | B 12288
    unsigned short* buf1 = buf0 + 20480;
    unsigned short* T2   = (unsigned short*)smem;       // epilogue overlay
    float* wsm = (float*)(smem + 51200);

    const int tid  = threadIdx.x;
    const int lane = tid & 63;
    const int wave = tid >> 6;
    const int g = blockIdx.x;
    const int h = g >> 7;                     // head 0..15
    const int blockM = (g & 127) * 128;       // M-tile fastest => same-XCD A sharing
    const int wm = wave >> 1, wn = wave & 1;  // wave tile 64x96
    const int K = 1024;

    const int kx = (tid >> 3) & 3;            // staging-side chunk XOR (verified r1)
    const unsigned short* gA = A  + (size_t)(blockM + (tid >> 2)) * K + ((tid & 3) ^ kx) * 8;
    const unsigned short* gB = Bt + (size_t)(h * 64 + (tid >> 2)) * K + ((tid & 3) ^ kx) * 8;

#define STAGE(p, ko) do {                                                   \
    unsigned short* lA = (p) + wave * 512;                                  \
    unsigned short* lB = (p) + 8192 + wave * 512;                           \
    gld_lds16(gA + (ko),                lA);           /* A h0 rows 0..63 */ \
    gld_lds16(gA + 65536 + (ko),        lA + 2048);    /* A h0 rows 64..127 */\
    gld_lds16(gA + 32 + (ko),           lA + 4096);    /* A h1 rows 0..63 */ \
    gld_lds16(gA + 65536 + 32 + (ko),   lA + 6144);    /* A h1 rows 64..127 */\
    gld_lds16(gB + (ko),                lB);           /* q h0 */            \
    gld_lds16(gB + 1048576 + (ko),      lB + 2048);    /* k h0 */            \
    gld_lds16(gB + 2097152 + (ko),      lB + 4096);    /* v h0 */            \
    gld_lds16(gB + 32 + (ko),           lB + 6144);    /* q h1 */            \
    gld_lds16(gB + 1048576 + 32 + (ko), lB + 8192);    /* k h1 */            \
    gld_lds16(gB + 2097152 + 32 + (ko), lB + 10240);   /* v h1 */ } while (0)

    floatx4 acc[4][6];
#pragma unroll
    for (int i = 0; i < 4; i++)
#pragma unroll
        for (int j = 0; j < 6; j++) acc[i][j] = (floatx4){0.f, 0.f, 0.f, 0.f};

    const int col  = lane & 15;
    const int quad = lane >> 4;
    const int qx = quad ^ ((col >> 1) & 3);   // read-side swizzled chunk (verified r1)
    const int aoff32 = (wm * 64 + col) * 32 + qx * 8;
    const int boff32 = 8192 + (wn * 96 + col) * 32 + qx * 8;   // B region base folded in

    // prologue: stage tile 0 into buf0 (10 loads in flight)
    STAGE(buf0, 0);

    for (int kt = 0; kt < 16; ++kt) {
        unsigned short* cur = (kt & 1) ? buf1 : buf0;
        unsigned short* nxt = (kt & 1) ? buf0 : buf1;
        if (kt < 15) {
            STAGE(nxt, (size_t)(kt + 1) * 64);            // 20 outstanding
            asm volatile("s_waitcnt vmcnt(10)" ::: "memory");  // tile kt landed; 10 in flight
        } else {
            asm volatile("s_waitcnt vmcnt(0)" ::: "memory");   // final drain
        }
        __builtin_amdgcn_sched_barrier(0);
        __builtin_amdgcn_s_barrier();                      // tile kt in LDS for ALL waves

        // ---- h0: read frags, MFMA ----
        short8 a0[4], b0v[6];
#pragma unroll
        for (int i = 0; i < 4; i++) a0[i] = *(const short8*)&cur[aoff32 + i * 512];
#pragma unroll
        for (int j = 0; j < 6; j++) b0v[j] = *(const short8*)&cur[boff32 + j * 512];
        asm volatile("s_waitcnt lgkmcnt(0)" ::: "memory");
        __builtin_amdgcn_sched_barrier(0);
        __builtin_amdgcn_s_setprio(1);
#pragma unroll
        for (int j = 0; j < 6; j++)
#pragma unroll
            for (int i = 0; i < 4; i++)
                acc[i][j] = __builtin_amdgcn_mfma_f32_16x16x32_bf16(a0[i], b0v[j], acc[i][j], 0, 0, 0);
        __builtin_amdgcn_s_setprio(0);

        // ---- h1: read frags, post-read barrier (overwrite-safe), MFMA ----
        short8 a1[4], b1v[6];
#pragma unroll
        for (int i = 0; i < 4; i++) a1[i] = *(const short8*)&cur[4096 + aoff32 + i * 512];
#pragma unroll
        for (int j = 0; j < 6; j++) b1v[j] = *(const short8*)&cur[6144 + boff32 + j * 512];
        asm volatile("s_waitcnt lgkmcnt(0)" ::: "memory");
        __builtin_amdgcn_sched_barrier(0);
        __builtin_amdgcn_s_barrier();                      // all waves done reading cur
        __builtin_amdgcn_s_setprio(1);
#pragma unroll
        for (int j = 0; j < 6; j++)
#pragma unroll
            for (int i = 0; i < 4; i++)
                acc[i][j] = __builtin_amdgcn_mfma_f32_16x16x32_bf16(a1[i], b1v[j], acc[i][j], 0, 0, 0);
        __builtin_amdgcn_s_setprio(0);
    }
#undef STAGE

    // 1) store tile transposed into overlay: T2[c][r], c = feature (q|k|v), r = M-row
    // (all LDS reads completed before kt=15's post-read barrier; overlay write is safe)
#pragma unroll
    for (int i = 0; i < 4; i++) {
#pragma unroll
        for (int j = 0; j < 6; j++) {
            int c  = wn * 96 + j * 16 + col;
            int r0 = wm * 64 + i * 16 + quad * 4;
            short4v pk;
            pk.x = (short)f2bf(acc[i][j][0]);
            pk.y = (short)f2bf(acc[i][j][1]);
            pk.z = (short)f2bf(acc[i][j][2]);
            pk.w = (short)f2bf(acc[i][j][3]);
            *(short4v*)&T2[c * T2_ST + r0] = pk;
        }
    }
    __syncthreads();

    // 2) scores + softmax: thread ib (<64) handles batch-row pair (2ib, 2ib+1)
    if (tid < 64) {
        const int ib = tid;
        float s00 = 0.f, s01 = 0.f, s10 = 0.f, s11 = 0.f;
#pragma unroll 8
        for (int d = 0; d < 64; d++) {
            unsigned int qp = *(const unsigned int*)&T2[d * T2_ST + 2 * ib];
            unsigned int kp = *(const unsigned int*)&T2[(64 + d) * T2_ST + 2 * ib];
            float q0 = lo_bf(qp), q1 = hi_bf(qp);
            float k0 = lo_bf(kp), k1 = hi_bf(kp);
            s00 += q0 * k0; s01 += q0 * k1;
            s10 += q1 * k0; s11 += q1 * k1;
        }
        const float sc = 0.125f;   // (1024/16)^-0.5
        s00 *= sc; s01 *= sc; s10 *= sc; s11 *= sc;
        float m0 = fmaxf(s00, s01), m1 = fmaxf(s10, s11);
        float e00 = __expf(s00 - m0), e01 = __expf(s01 - m0);
        float e10 = __expf(s10 - m1), e11 = __expf(s11 - m1);
        float i0 = 1.f / (e00 + e01), i1 = 1.f / (e10 + e11);
        wsm[ib * 4 + 0] = e00 * i0; wsm[ib * 4 + 1] = e01 * i0;
        wsm[ib * 4 + 2] = e10 * i1; wsm[ib * 4 + 3] = e11 * i1;
    }
    __syncthreads();

    // 3) out = attn @ v, write global (128 rows x 64 cols = 1024 8-elem chunks)
#pragma unroll
    for (int gg = 0; gg < 4; gg++) {
        int chunk = gg * 256 + tid;
        int r = chunk >> 3;
        int dc = (chunk & 7) * 8;
        int ib = r >> 1, n = r & 1;
        float w0 = wsm[ib * 4 + n * 2 + 0];
        float w1 = wsm[ib * 4 + n * 2 + 1];
        short8 o;
#pragma unroll
        for (int dd = 0; dd < 8; dd++) {
            unsigned int vp = *(const unsigned int*)&T2[(128 + dc + dd) * T2_ST + 2 * ib];
            o[dd] = (short)f2bf(w0 * lo_bf(vp) + w1 * hi_bf(vp));
        }
        *(short8*)&attn_out[(size_t)(blockM + r) * 1024 + h * 64 + dc] = o;
    }
}

// ---------- LayerNorm(2048) + residual ----------
__global__ __launch_bounds__(256) void ln_res_kernel(const unsigned short* __restrict__ proj,
                                                     const unsigned short* __restrict__ xres,
                                                     const float* __restrict__ gamma,
                                                     const float* __restrict__ beta,
                                                     float* __restrict__ out) {
    const int b = blockIdx.x;
    const int tid = threadIdx.x;
    const size_t base = (size_t)b * 2048;
    short8 p8 = ((const short8*)(proj + base))[tid];
    float pv[8];
#pragma unroll
    for (int e = 0; e < 8; e++) pv[e] = bf2f((unsigned short)p8[e]);
    float s = 0.f, ss = 0.f;
#pragma unroll
    for (int e = 0; e < 8; e++) { s += pv[e]; ss += pv[e] * pv[e]; }
#pragma unroll
    for (int off = 32; off > 0; off >>= 1) {
        s  += __shfl_xor(s, off);
        ss += __shfl_xor(ss, off);
    }
    __shared__ float red[8];
    const int wave = tid >> 6;
    if ((tid & 63) == 0) { red[wave] = s; red[4 + wave] = ss; }
    __syncthreads();
    s  = red[0] + red[1] + red[2] + red[3];
    ss = red[4] + red[5] + red[6] + red[7];
    const float mean = s * (1.0f / 2048.0f);
    const float var  = ss * (1.0f / 2048.0f) - mean * mean;
    const float rstd = rsqrtf(var + 1e-5f);

    const float4* g4 = (const float4*)gamma;
    const float4* b4 = (const float4*)beta;
    float4 g0 = g4[2 * tid], g1 = g4[2 * tid + 1];
    float4 be0 = b4[2 * tid], be1 = b4[2 * tid + 1];
    short8 r8 = ((const short8*)(xres + base))[tid];
    float4 o0, o1;
    o0.x = (pv[0] - mean) * rstd * g0.x + be0.x + bf2f((unsigned short)r8[0]);
    o0.y = (pv[1] - mean) * rstd * g0.y + be0.y + bf2f((unsigned short)r8[1]);
    o0.z = (pv[2] - mean) * rstd * g0.z + be0.z + bf2f((unsigned short)r8[2]);
    o0.w = (pv[3] - mean) * rstd * g0.w + be0.w + bf2f((unsigned short)r8[3]);
    o1.x = (pv[4] - mean) * rstd * g1.x + be1.x + bf2f((unsigned short)r8[4]);
    o1.y = (pv[5] - mean) * rstd * g1.y + be1.y + bf2f((unsigned short)r8[5]);
    o1.z = (pv[6] - mean) * rstd * g1.z + be1.z + bf2f((unsigned short)r8[6]);
    o1.w = (pv[7] - mean) * rstd * g1.w + be1.w + bf2f((unsigned short)r8[7]);
    float4* op = (float4*)(out + base);
    op[2 * tid] = o0;
    op[2 * tid + 1] = o1;
}

// ---------- launch ----------
extern "C" void kernel_launch(void* const* d_in, const int* in_sizes, int n_in,
                              void* d_out, int out_size, void* d_ws, size_t ws_size,
                              hipStream_t stream) {
    (void)in_sizes; (void)n_in; (void)out_size; (void)ws_size;
    const float* features1 = (const float*)d_in[0];
    const float* features2 = (const float*)d_in[1];
    const float* W1   = (const float*)d_in[2];
    const float* b1   = (const float*)d_in[3];
    const float* W2   = (const float*)d_in[4];
    const float* b2   = (const float*)d_in[5];
    const float* Wqkv = (const float*)d_in[6];
    const float* Wout = (const float*)d_in[7];
    const float* bout = (const float*)d_in[8];
    const float* gamma = (const float*)d_in[9];
    const float* beta  = (const float*)d_in[10];
    float* out = (float*)d_out;

    static bool qkv3_init = false;
    if (!qkv3_init) {
        (void)hipFuncSetAttribute((const void*)gemm_qkv_attn3,
                                  hipFuncAttributeMaxDynamicSharedMemorySize,
                                  QKV_LDS_BYTES);
        qkv3_init = true;
    }

    // B=8192, IMG=2048, Q=768, H=1024
    char* ws = (char*)d_ws;
    unsigned short* f1b   = (unsigned short*)(ws);                 // 32 MiB
    unsigned short* f2b   = (unsigned short*)(ws + 33554432);      // 12 MiB
    unsigned short* W1t   = (unsigned short*)(ws + 46137344);      // 4 MiB   [1024][2048]
    unsigned short* W2t   = (unsigned short*)(ws + 50331648);      // 1.5 MiB [1024][768]
    unsigned short* Wqkvt = (unsigned short*)(ws + 51904512);      // 6 MiB   [3072][1024]
    unsigned short* Woutt = (unsigned short*)(ws + 58195968);      // 2 MiB   [1024][1024]
    unsigned short* xb    = (unsigned short*)(ws + 60293120);      // 32 MiB  [16384][1024]
    unsigned short* attn  = (unsigned short*)(ws + 93847552);      // 32 MiB  [16384][1024]
    unsigned short* projb = (unsigned short*)(ws + 127401984);     // 32 MiB  [16384][1024] bf16

    // 1) unified prep (feature cvt + weight transposes)
    prep_kernel<<<9088, 256, 0, stream>>>(features1, features2, f1b, f2b,
                                          W1, W1t, W2, W2t, Wqkv, Wqkvt, Wout, Woutt);
    // 2) f1/f2 modality GEMMs
    gemm_f12<<<dim3(64, 8, 2), 256, 0, stream>>>(f1b, W1t, b1, f2b, W2t, b2, xb);
    // 3) fused qkv GEMM + attention (dbuf + counted vmcnt)
    gemm_qkv_attn3<<<2048, 256, QKV_LDS_BYTES, stream>>>(xb, Wqkvt, attn);
    // 4) proj = attn @ Wout + bout -> bf16
    gemm_proj<<<dim3(128, 8), 256, 0, stream>>>(attn, Woutt, bout, projb);
    // 5) LayerNorm + residual
    ln_res_kernel<<<8192, 256, 0, stream>>>(projb, xb, gamma, beta, out);
}